// Round 6
// baseline (17042.181 us; speedup 1.0000x reference)
//
#include <hip/hip_runtime.h>
#include <hip/hip_cooperative_groups.h>

namespace cg = cooperative_groups;

#define N4K 4096
#define DFEAT 256
constexpr float P_UNIF = 1.0f / 4096.0f;

typedef __attribute__((ext_vector_type(8))) short bf16x8;
typedef __attribute__((ext_vector_type(4))) float f32x4;

__device__ __forceinline__ float bfl(unsigned u) { return __uint_as_float(u << 16); }
__device__ __forceinline__ float bfh(unsigned u) { return __uint_as_float(u & 0xffff0000u); }
__device__ __forceinline__ unsigned short f2bf(float f) {
  unsigned u = __float_as_uint(f);
  u += 0x7fffu + ((u >> 16) & 1u);   // RNE
  return (unsigned short)(u >> 16);
}
__device__ __forceinline__ void load_lds16(const void* g, void* l) {
  __builtin_amdgcn_global_load_lds(
      (const __attribute__((address_space(1))) void*)g,
      (__attribute__((address_space(3))) void*)l, 16, 0, 0);
}

// ---------------- row-normalize + cast to bf16 -------------------------------
__global__ void k_normalize(const float* __restrict__ in, unsigned short* __restrict__ out) {
  const int wv = threadIdx.x >> 6, lane = threadIdx.x & 63;
  const int row = blockIdx.x * 4 + wv;
  const float4 v = ((const float4*)(in + (size_t)row * DFEAT))[lane];
  float ss = v.x * v.x + v.y * v.y + v.z * v.z + v.w * v.w;
#pragma unroll
  for (int off = 32; off; off >>= 1) ss += __shfl_xor(ss, off);
  const float inv = rsqrtf(ss);
  unsigned a = (unsigned)f2bf(v.x * inv) | ((unsigned)f2bf(v.y * inv) << 16);
  unsigned b = (unsigned)f2bf(v.z * inv) | ((unsigned)f2bf(v.w * inv) << 16);
  ((uint2*)(out + (size_t)row * DFEAT))[lane] = make_uint2(a, b);
}

// ---------------- bf16 transpose [R x C] -> [C x R], 64x64 tiles -------------
__global__ void k_transpose(const unsigned short* __restrict__ in,
                            unsigned short* __restrict__ out, int R, int C) {
  __shared__ unsigned short t[64][65];
  const int tid = threadIdx.x;
  const int tx = tid & 63, ty = tid >> 6;
  const int c0 = blockIdx.x * 64, r0 = blockIdx.y * 64;
#pragma unroll
  for (int k = 0; k < 16; k++) {
    const int r = ty * 16 + k;
    t[r][tx] = in[(size_t)(r0 + r) * C + c0 + tx];
  }
  __syncthreads();
#pragma unroll
  for (int k = 0; k < 16; k++) {
    const int r = ty * 16 + k;
    out[(size_t)(c0 + r) * R + r0 + tx] = t[tx][r];
  }
}

// ---------------- generic zero -----------------------------------------------
__global__ void k_zerof(float* __restrict__ p, int n) {
  const int i = blockIdx.x * 256 + threadIdx.x;
  if (i < n) p[i] = 0.0f;
}

// ---------------- m97-pattern bf16 GEMM: C = A @ B^T -------------------------
// mode 0: bf16 out = acc
// mode 2: bf16 out = exp(sArg*acc - ctE[col]), sArg = 40/((1+dm1)(1+dm2))
// mode 3: fp32 outf[(z*gridDim.y*128 + row)*ldo + col] = acc  (K-split partials)
// mode 4: stats only: atomicAdd colsum/colsumsq of acc into psum/psq,
//         atomicMax(-acc) into dmx. No matrix output.
__global__ __launch_bounds__(256) void k_gemm_bt(
    const unsigned short* __restrict__ A, const unsigned short* __restrict__ B,
    int ld, int kChunk, unsigned short* __restrict__ out, float* __restrict__ outf,
    int ldo, int mode, const float* __restrict__ ctE,
    const float* __restrict__ dm1, const float* __restrict__ dm2,
    float* __restrict__ psum, float* __restrict__ psq, float* __restrict__ dmx)
{
  __shared__ unsigned short Als[128 * 32];
  __shared__ unsigned short Bls[128 * 32];
  __shared__ float cs[128], cq[128];
  __shared__ float wmx[4];
  const int tid = threadIdx.x;
  const int w = tid >> 6, lane = tid & 63;
  const int wr = w >> 1, wc = w & 1;                 // 2x2 waves, 64x64 each
  const int mbase = blockIdx.y * 128, nbase = blockIdx.x * 128;
  const int kBase = blockIdx.z * kChunk;

  if (mode == 4 && tid < 128) { cs[tid] = 0.f; cq[tid] = 0.f; }

  const f32x4 fz = {0.f, 0.f, 0.f, 0.f};
  f32x4 acc[4][4];
#pragma unroll
  for (int m = 0; m < 4; m++)
#pragma unroll
    for (int n = 0; n < 4; n++) acc[m][n] = fz;

  const int sRow = lane >> 2;            // 0..15
  const int sCol = (lane & 3) * 8;       // 0,8,16,24
  const unsigned short* gA = A + (size_t)(mbase + w * 32 + sRow) * ld + sCol;
  const unsigned short* gB = B + (size_t)(nbase + w * 32 + sRow) * ld + sCol;
  unsigned short* lA0 = &Als[(w * 2 + 0) * 512];
  unsigned short* lA1 = &Als[(w * 2 + 1) * 512];
  unsigned short* lB0 = &Bls[(w * 2 + 0) * 512];
  unsigned short* lB1 = &Bls[(w * 2 + 1) * 512];

  const int rA = lane & 15, kg = (lane >> 4) * 8;

  for (int k0 = kBase; k0 < kBase + kChunk; k0 += 32) {
    __syncthreads();
    load_lds16(gA + k0, lA0);
    load_lds16(gA + (size_t)16 * ld + k0, lA1);
    load_lds16(gB + k0, lB0);
    load_lds16(gB + (size_t)16 * ld + k0, lB1);
    __syncthreads();
    bf16x8 a[4], b[4];
#pragma unroll
    for (int m = 0; m < 4; m++)
      a[m] = *(const bf16x8*)&Als[(wr * 64 + m * 16 + rA) * 32 + kg];
#pragma unroll
    for (int n = 0; n < 4; n++)
      b[n] = *(const bf16x8*)&Bls[(wc * 64 + n * 16 + rA) * 32 + kg];
#pragma unroll
    for (int m = 0; m < 4; m++)
#pragma unroll
      for (int n = 0; n < 4; n++)
        acc[m][n] = __builtin_amdgcn_mfma_f32_16x16x32_bf16(a[m], b[n], acc[m][n], 0, 0, 0);
  }

  // C/D layout: col = lane&15, row = (lane>>4)*4 + r   [m89-verified]
  const int crow0 = mbase + wr * 64 + (lane >> 4) * 4;
  const int ccol0 = nbase + wc * 64 + (lane & 15);

  if (mode == 4) {
    float mx = -2.0f;
#pragma unroll
    for (int n = 0; n < 4; n++) {
      float sv = 0.f, sq2 = 0.f;
#pragma unroll
      for (int m = 0; m < 4; m++)
#pragma unroll
        for (int r = 0; r < 4; r++) {
          const float val = acc[m][n][r];
          sv += val; sq2 += val * val;
          mx = fmaxf(mx, -val);
        }
      const int lcol = wc * 64 + n * 16 + (lane & 15);
      atomicAdd(&cs[lcol], sv);
      atomicAdd(&cq[lcol], sq2);
    }
#pragma unroll
    for (int off = 32; off; off >>= 1) mx = fmaxf(mx, __shfl_xor(mx, off));
    if (lane == 0) wmx[w] = mx;
    __syncthreads();
    if (tid == 0)
      atomicMax((int*)dmx, __float_as_int(fmaxf(fmaxf(wmx[0], wmx[1]), fmaxf(wmx[2], wmx[3]))));
    if (tid < 128) {
      atomicAdd(&psum[nbase + tid], cs[tid]);
      atomicAdd(&psq[nbase + tid], cq[tid]);
    }
    return;
  }

  float sArg = 0.f;
  if (mode == 2) sArg = 40.0f / ((1.0f + *dm1) * (1.0f + *dm2));
#pragma unroll
  for (int m = 0; m < 4; m++) {
#pragma unroll
    for (int n = 0; n < 4; n++) {
      const int col = ccol0 + n * 16;
      const float cv = (mode == 2) ? ctE[col] : 0.0f;
#pragma unroll
      for (int r = 0; r < 4; r++) {
        const int row = crow0 + m * 16 + r;
        float val = acc[m][n][r];
        if (mode == 3) {
          outf[((size_t)blockIdx.z * (gridDim.y * 128) + row) * ldo + col] = val;
        } else {
          if (mode == 2) val = __expf(fmaf(sArg, val, -cv));
          out[(size_t)row * ldo + col] = f2bf(val);
        }
      }
    }
  }
}

// ctE_j = [ (1-2*g2_j+s2_j)/m2^2 + (2/(m1*m2))*g2_j ] / eps
__global__ void k_ctfinal(const float* __restrict__ psum, const float* __restrict__ psq,
                          const float* __restrict__ dm1p, const float* __restrict__ dm2p,
                          float* __restrict__ ctE) {
  const int j = blockIdx.x * 256 + threadIdx.x;
  const float g2 = psum[j] * (1.0f / N4K);
  const float s2 = psq[j] * (1.0f / N4K);
  const float m1 = 1.0f + *dm1p, m2 = 1.0f + *dm2p;
  ctE[j] = ((1.0f - 2.0f * g2 + s2) / (m2 * m2) + (2.0f / (m1 * m2)) * g2) * 20.0f;
}

// ---------------- it=0: Yt0[d][i] = (1/N^2) * rowsum(X2t[d]) -----------------
__global__ void k_yt0(const unsigned short* __restrict__ X2t, unsigned short* __restrict__ Yt) {
  __shared__ float red[256];
  const int d = blockIdx.x, t = threadIdx.x;
  const unsigned short* row = X2t + (size_t)d * N4K;
  const uint4 q = *(const uint4*)&row[t * 16];
  const uint4 q2 = *(const uint4*)&row[t * 16 + 8];
  float s = bfl(q.x) + bfh(q.x) + bfl(q.y) + bfh(q.y) + bfl(q.z) + bfh(q.z)
          + bfl(q.w) + bfh(q.w) + bfl(q2.x) + bfh(q2.x) + bfl(q2.y) + bfh(q2.y)
          + bfl(q2.z) + bfh(q2.z) + bfl(q2.w) + bfh(q2.w);
  red[t] = s;
  __syncthreads();
  for (int st = 128; st > 0; st >>= 1) {
    if (t < st) red[t] += red[t + st];
    __syncthreads();
  }
  const unsigned short pv = f2bf(red[0] * (P_UNIF * P_UNIF));
  const unsigned pk = (unsigned)pv | ((unsigned)pv << 16);
  uint4* dst = (uint4*)(Yt + (size_t)d * N4K);
  dst[t] = make_uint4(pk, pk, pk, pk);
  dst[t + 256] = make_uint4(pk, pk, pk, pk);
}

// ---------------- X2vt[d][i] = X2t[d][i] * v[i] ------------------------------
__global__ void k_x2v(const unsigned short* __restrict__ X2t, const float* __restrict__ v,
                      unsigned short* __restrict__ X2vt) {
  const int d = blockIdx.x, t = threadIdx.x;
  const int i0 = t * 16;
  const unsigned short* src = X2t + (size_t)d * N4K + i0;
  unsigned short* dst = X2vt + (size_t)d * N4K + i0;
  const uint4 a = *(const uint4*)src;
  const uint4 b = *(const uint4*)(src + 8);
  const float4 v0 = *(const float4*)&v[i0];
  const float4 v1 = *(const float4*)&v[i0 + 4];
  const float4 v2 = *(const float4*)&v[i0 + 8];
  const float4 v3 = *(const float4*)&v[i0 + 12];
  unsigned r0 = (unsigned)f2bf(bfl(a.x) * v0.x) | ((unsigned)f2bf(bfh(a.x) * v0.y) << 16);
  unsigned r1 = (unsigned)f2bf(bfl(a.y) * v0.z) | ((unsigned)f2bf(bfh(a.y) * v0.w) << 16);
  unsigned r2 = (unsigned)f2bf(bfl(a.z) * v1.x) | ((unsigned)f2bf(bfh(a.z) * v1.y) << 16);
  unsigned r3 = (unsigned)f2bf(bfl(a.w) * v1.z) | ((unsigned)f2bf(bfh(a.w) * v1.w) << 16);
  unsigned r4 = (unsigned)f2bf(bfl(b.x) * v2.x) | ((unsigned)f2bf(bfh(b.x) * v2.y) << 16);
  unsigned r5 = (unsigned)f2bf(bfl(b.y) * v2.z) | ((unsigned)f2bf(bfh(b.y) * v2.w) << 16);
  unsigned r6 = (unsigned)f2bf(bfl(b.z) * v3.x) | ((unsigned)f2bf(bfh(b.z) * v3.y) << 16);
  unsigned r7 = (unsigned)f2bf(bfl(b.w) * v3.z) | ((unsigned)f2bf(bfh(b.w) * v3.w) << 16);
  *(uint4*)dst = make_uint4(r0, r1, r2, r3);
  *(uint4*)(dst + 8) = make_uint4(r4, r5, r6, r7);
}

// ---------------- reduce 8 K-chunk partials of Y, apply u, transpose ---------
// Yp: [8][4096][256] fp32 -> Yt: [256][4096] bf16, Yt[d][i] = u[i]*sum_z Yp[z][i][d]
__global__ void k_redY(const float* __restrict__ Yp, const float* __restrict__ u,
                       unsigned short* __restrict__ Yt) {
  __shared__ float t[64][65];
  const int tid = threadIdx.x;
  const int tx = tid & 63, ty = tid >> 6;
  const int r0 = blockIdx.x * 64, c0 = blockIdx.y * 64;
#pragma unroll
  for (int k = 0; k < 16; k++) {
    const int r = ty * 16 + k;
    const size_t off = (size_t)(r0 + r) * 256 + c0 + tx;
    float s = 0.f;
#pragma unroll
    for (int z = 0; z < 8; z++) s += Yp[(size_t)z * (N4K * 256) + off];
    t[r][tx] = s;
  }
  __syncthreads();
  const float uu = u[r0 + tx];
#pragma unroll
  for (int k = 0; k < 16; k++) {
    const int r = ty * 16 + k;
    Yt[(size_t)(c0 + r) * N4K + r0 + tx] = f2bf(t[tx][r] * uu);
  }
}

// ---------------- reduce 16 K-chunk partials of PT ---------------------------
__global__ void k_redPT(const float* __restrict__ Pp, unsigned short* __restrict__ PTb) {
  const int idx = blockIdx.x * 256 + threadIdx.x;
  float s = 0.f;
#pragma unroll
  for (int z = 0; z < 16; z++) s += Pp[z * 65536 + idx];
  PTb[idx] = f2bf(s);
}

// ---------------- persistent cooperative Sinkhorn: 20 iterations -------------
// 256 blocks x 512 threads, 1 block/CU. Block b owns rows [16b,16b+16) in LDS.
__global__ __launch_bounds__(512, 1) void k_sink20(
    const unsigned short* __restrict__ Km, float* __restrict__ u,
    float* __restrict__ v, float* __restrict__ partials)
{
  __shared__ unsigned short Kl[16 * N4K];   // 128 KiB
  __shared__ float vs[N4K];                 // 16 KiB
  __shared__ float us[16];
  const int tid = threadIdx.x;
  const int b = blockIdx.x;
  const int row0 = b * 16;
  {
    const uint4* g = (const uint4*)(Km + (size_t)row0 * N4K);
    uint4* l = (uint4*)Kl;
#pragma unroll
    for (int i = 0; i < 16; i++) l[tid + 512 * i] = g[tid + 512 * i];
  }
  for (int i = tid; i < N4K; i += 512) vs[i] = 1.0f;
  __syncthreads();
  cg::grid_group grid = cg::this_grid();
  const int wv = tid >> 6, lane = tid & 63;

  for (int s = 0; s < 20; s++) {
    // phase A: u = p/(K v) for rows 2wv, 2wv+1 (LDS)
    {
      const unsigned short* rA = &Kl[(wv * 2) * N4K];
      const unsigned short* rB = rA + N4K;
      float accA = 0.f, accB = 0.f;
#pragma unroll
      for (int p = 0; p < 8; p++) {
        const int j0 = p * 512 + lane * 8;
        const uint4 qa = *(const uint4*)&rA[j0];
        const uint4 qb = *(const uint4*)&rB[j0];
        const float4 xa = *(const float4*)&vs[j0];
        const float4 xb = *(const float4*)&vs[j0 + 4];
        accA += bfl(qa.x) * xa.x + bfh(qa.x) * xa.y + bfl(qa.y) * xa.z + bfh(qa.y) * xa.w
              + bfl(qa.z) * xb.x + bfh(qa.z) * xb.y + bfl(qa.w) * xb.z + bfh(qa.w) * xb.w;
        accB += bfl(qb.x) * xa.x + bfh(qb.x) * xa.y + bfl(qb.y) * xa.z + bfh(qb.y) * xa.w
              + bfl(qb.z) * xb.x + bfh(qb.z) * xb.y + bfl(qb.w) * xb.z + bfh(qb.w) * xb.w;
      }
#pragma unroll
      for (int off = 32; off; off >>= 1) {
        accA += __shfl_xor(accA, off);
        accB += __shfl_xor(accB, off);
      }
      if (lane == 0) {
        us[wv * 2] = P_UNIF / accA;
        us[wv * 2 + 1] = P_UNIF / accB;
      }
    }
    __syncthreads();
    // phase B: partial colsums of K^T u for 8 cols/thread (LDS reads)
    {
      const int c0 = tid * 8;
      float a0 = 0, a1 = 0, a2 = 0, a3 = 0, a4 = 0, a5 = 0, a6 = 0, a7 = 0;
#pragma unroll
      for (int r = 0; r < 16; r++) {
        const float ur = us[r];
        const uint4 q = *(const uint4*)&Kl[r * N4K + c0];
        a0 += ur * bfl(q.x); a1 += ur * bfh(q.x);
        a2 += ur * bfl(q.y); a3 += ur * bfh(q.y);
        a4 += ur * bfl(q.z); a5 += ur * bfh(q.z);
        a6 += ur * bfl(q.w); a7 += ur * bfh(q.w);
      }
      float* pp = partials + (size_t)b * N4K + c0;
      *(float4*)pp = make_float4(a0, a1, a2, a3);
      *(float4*)(pp + 4) = make_float4(a4, a5, a6, a7);
    }
    __threadfence();
    grid.sync();
    // phase C: reduce cols [row0,row0+16): 32 threads per col
    {
      const int cl = tid >> 5, g = tid & 31;
      const int col = row0 + cl;
      float sum = 0.f;
      const float* p = partials + (size_t)g * 8 * N4K + col;
#pragma unroll
      for (int k = 0; k < 8; k++) sum += p[(size_t)k * N4K];
#pragma unroll
      for (int off = 16; off; off >>= 1) sum += __shfl_xor(sum, off);
      if (g == 0) v[col] = P_UNIF / sum;
    }
    __threadfence();
    grid.sync();
    for (int i = tid; i < N4K; i += 512) vs[i] = v[i];
    __syncthreads();
  }
  if (tid < 16) u[row0 + tid] = us[tid];
}

// ---------------- loss = -sum log(u_i K_ii v_i + 1e-10) ----------------------
__global__ void k_loss(const unsigned short* __restrict__ K, const float* __restrict__ u,
                       const float* __restrict__ v, float* __restrict__ out) {
  const int tid = threadIdx.x;
  float acc = 0.f;
  for (int i = tid; i < N4K; i += 256) {
    const float d = u[i] * bfl((unsigned)K[(size_t)i * (N4K + 1)]) * v[i];
    acc += logf(d + 1e-10f);
  }
  __shared__ float red[256];
  red[tid] = acc;
  __syncthreads();
  for (int st = 128; st > 0; st >>= 1) {
    if (tid < st) red[tid] += red[tid + st];
    __syncthreads();
  }
  if (tid == 0) out[0] = -red[0];
}

// ============================================================================
extern "C" void kernel_launch(void* const* d_in, const int* in_sizes, int n_in,
                              void* d_out, int out_size, void* d_ws, size_t ws_size,
                              hipStream_t stream) {
  const float* f1 = (const float*)d_in[0];
  const float* f2 = (const float*)d_in[1];
  float* out = (float*)d_out;

  char* w = (char*)d_ws;
  const size_t NN = (size_t)N4K * N4K;
  unsigned short* X1 = (unsigned short*)w;   w += (size_t)N4K * DFEAT * 2;
  unsigned short* X2 = (unsigned short*)w;   w += (size_t)N4K * DFEAT * 2;
  unsigned short* X1t = (unsigned short*)w;  w += (size_t)N4K * DFEAT * 2;
  unsigned short* X2t = (unsigned short*)w;  w += (size_t)N4K * DFEAT * 2;
  unsigned short* X2vt = (unsigned short*)w; w += (size_t)N4K * DFEAT * 2;
  unsigned short* Zb = (unsigned short*)w;   w += (size_t)N4K * DFEAT * 2;
  unsigned short* Yt = (unsigned short*)w;   w += (size_t)N4K * DFEAT * 2;
  unsigned short* PTb = (unsigned short*)w;  w += (size_t)DFEAT * DFEAT * 2;
  unsigned short* KA = (unsigned short*)w;   w += NN * 2;
  unsigned short* KB = (unsigned short*)w;   w += NN * 2;
  float* Yp = (float*)w;    w += (size_t)8 * N4K * DFEAT * 4;   // 32 MB
  float* Pp = (float*)w;    w += (size_t)16 * DFEAT * DFEAT * 4; // 4 MB
  float* spart = (float*)w; w += (size_t)256 * N4K * 4;          // 4 MB
  float* stats = (float*)w; w += (size_t)16640 * 4;
  float* uvec = (float*)w;  w += N4K * 4;
  float* vvec = (float*)w;  w += N4K * 4;
  float* ctE = (float*)w;   w += N4K * 4;

  float* psum2 = stats;
  float* psq2 = stats + 4096;
  float* psumD = stats + 8192;
  float* psqD = stats + 12288;
  float* dmax1 = stats + 16384;
  float* dmax2 = stats + 16385;

  const dim3 b256(256);

  k_normalize<<<1024, b256, 0, stream>>>(f1, X1);
  k_normalize<<<1024, b256, 0, stream>>>(f2, X2);
  k_transpose<<<dim3(4, 64), b256, 0, stream>>>(X1, X1t, N4K, DFEAT);
  k_transpose<<<dim3(4, 64), b256, 0, stream>>>(X2, X2t, N4K, DFEAT);
  k_zerof<<<65, b256, 0, stream>>>(stats, 16640);

  // Gram stats (mode 4, no matrix output): G1 -> dmax1; G2 -> colsums + dmax2
  k_gemm_bt<<<dim3(32, 32, 1), b256, 0, stream>>>(X1, X1, DFEAT, DFEAT, nullptr, nullptr,
                                                  0, 4, nullptr, nullptr, nullptr,
                                                  psumD, psqD, dmax1);
  k_gemm_bt<<<dim3(32, 32, 1), b256, 0, stream>>>(X2, X2, DFEAT, DFEAT, nullptr, nullptr,
                                                  0, 4, nullptr, nullptr, nullptr,
                                                  psum2, psq2, dmax2);
  k_ctfinal<<<16, b256, 0, stream>>>(psum2, psq2, dmax1, dmax2, ctE);

  unsigned short* Kprev = nullptr;
  for (int it = 0; it < 5; it++) {
    if (it == 0) {
      // T0 = p q^T is rank-1: Yt0[d][i] = (1/N^2) rowsum(X2t[d])
      k_yt0<<<256, b256, 0, stream>>>(X2t, Yt);
    } else {
      // T = u (.) Kprev (.) v implicitly: Y = diag(u) Kprev (diag(v) X2)
      k_x2v<<<256, b256, 0, stream>>>(X2t, vvec, X2vt);
      k_gemm_bt<<<dim3(2, 32, 8), b256, 0, stream>>>(Kprev, X2vt, N4K, 512, nullptr, Yp,
                                                     DFEAT, 3, nullptr, nullptr, nullptr,
                                                     nullptr, nullptr, nullptr);
      k_redY<<<dim3(64, 4), b256, 0, stream>>>(Yp, uvec, Yt);
    }
    // PT = Y^T X1 (K-split 16)
    k_gemm_bt<<<dim3(2, 2, 16), b256, 0, stream>>>(Yt, X1t, N4K, 256, nullptr, Pp,
                                                   DFEAT, 3, nullptr, nullptr, nullptr,
                                                   nullptr, nullptr, nullptr);
    k_redPT<<<256, b256, 0, stream>>>(Pp, PTb);
    // Z = X1 P
    k_gemm_bt<<<dim3(2, 32, 1), b256, 0, stream>>>(X1, PTb, DFEAT, DFEAT, Zb, nullptr,
                                                   DFEAT, 0, nullptr, nullptr, nullptr,
                                                   nullptr, nullptr, nullptr);
    // K = exp(sArg * Z X2^T - ctE_j)
    unsigned short* Knew = (Kprev == KA) ? KB : KA;
    k_gemm_bt<<<dim3(32, 32, 1), b256, 0, stream>>>(Zb, X2, DFEAT, DFEAT, Knew, nullptr,
                                                    N4K, 2, ctE, dmax1, dmax2,
                                                    nullptr, nullptr, nullptr);
    // 20 Sinkhorn iterations in one persistent cooperative kernel
    {
      void* kargs[] = {(void*)&Knew, (void*)&uvec, (void*)&vvec, (void*)&spart};
      hipLaunchCooperativeKernel((const void*)k_sink20, dim3(256), dim3(512),
                                 kargs, 0, stream);
    }
    Kprev = Knew;
  }
  k_loss<<<1, b256, 0, stream>>>(Kprev, uvec, vvec, out);
}

// Round 8
// 1918.843 us; speedup vs baseline: 8.8815x; 8.8815x over previous
//
#include <hip/hip_runtime.h>

#define N4K 4096
#define DFEAT 256
constexpr float P_UNIF = 1.0f / 4096.0f;

typedef __attribute__((ext_vector_type(8))) short bf16x8;
typedef __attribute__((ext_vector_type(4))) float f32x4;

__device__ __forceinline__ float bfl(unsigned u) { return __uint_as_float(u << 16); }
__device__ __forceinline__ float bfh(unsigned u) { return __uint_as_float(u & 0xffff0000u); }
__device__ __forceinline__ unsigned short f2bf(float f) {
  unsigned u = __float_as_uint(f);
  u += 0x7fffu + ((u >> 16) & 1u);   // RNE
  return (unsigned short)(u >> 16);
}
__device__ __forceinline__ void load_lds16(const void* g, void* l) {
  __builtin_amdgcn_global_load_lds(
      (const __attribute__((address_space(1))) void*)g,
      (__attribute__((address_space(3))) void*)l, 16, 0, 0);
}

// ---------------- row-normalize + cast to bf16 -------------------------------
__global__ void k_normalize(const float* __restrict__ in, unsigned short* __restrict__ out) {
  const int wv = threadIdx.x >> 6, lane = threadIdx.x & 63;
  const int row = blockIdx.x * 4 + wv;
  const float4 v = ((const float4*)(in + (size_t)row * DFEAT))[lane];
  float ss = v.x * v.x + v.y * v.y + v.z * v.z + v.w * v.w;
#pragma unroll
  for (int off = 32; off; off >>= 1) ss += __shfl_xor(ss, off);
  const float inv = rsqrtf(ss);
  unsigned a = (unsigned)f2bf(v.x * inv) | ((unsigned)f2bf(v.y * inv) << 16);
  unsigned b = (unsigned)f2bf(v.z * inv) | ((unsigned)f2bf(v.w * inv) << 16);
  ((uint2*)(out + (size_t)row * DFEAT))[lane] = make_uint2(a, b);
}

// ---------------- bf16 transpose [R x C] -> [C x R], 64x64 tiles -------------
__global__ void k_transpose(const unsigned short* __restrict__ in,
                            unsigned short* __restrict__ out, int R, int C) {
  __shared__ unsigned short t[64][65];
  const int tid = threadIdx.x;
  const int tx = tid & 63, ty = tid >> 6;
  const int c0 = blockIdx.x * 64, r0 = blockIdx.y * 64;
#pragma unroll
  for (int k = 0; k < 16; k++) {
    const int r = ty * 16 + k;
    t[r][tx] = in[(size_t)(r0 + r) * C + c0 + tx];
  }
  __syncthreads();
#pragma unroll
  for (int k = 0; k < 16; k++) {
    const int r = ty * 16 + k;
    out[(size_t)(c0 + r) * R + r0 + tx] = t[tx][r];
  }
}

// ---------------- generic zero -----------------------------------------------
__global__ void k_zerof(float* __restrict__ p, int n) {
  const int i = blockIdx.x * 256 + threadIdx.x;
  if (i < n) p[i] = 0.0f;
}

// ---------------- m97-pattern bf16 GEMM: C = A @ B^T -------------------------
// mode 0: bf16 out = acc
// mode 2: bf16 out = exp(sArg*acc - ctE[col]), sArg = 40/((1+dm1)(1+dm2))
// mode 3: fp32 outf[(z*gridDim.y*128 + row)*ldo + col] = acc  (K-split partials)
// mode 4: stats only: colsum/colsumsq of acc -> psum/psq, max(-acc) -> dmx
__global__ __launch_bounds__(256) void k_gemm_bt(
    const unsigned short* __restrict__ A, const unsigned short* __restrict__ B,
    int ld, int kChunk, unsigned short* __restrict__ out, float* __restrict__ outf,
    int ldo, int mode, const float* __restrict__ ctE,
    const float* __restrict__ dm1, const float* __restrict__ dm2,
    float* __restrict__ psum, float* __restrict__ psq, float* __restrict__ dmx)
{
  __shared__ unsigned short Als[128 * 32];
  __shared__ unsigned short Bls[128 * 32];
  __shared__ float cs[128], cq[128];
  __shared__ float wmx[4];
  const int tid = threadIdx.x;
  const int w = tid >> 6, lane = tid & 63;
  const int wr = w >> 1, wc = w & 1;                 // 2x2 waves, 64x64 each
  const int mbase = blockIdx.y * 128, nbase = blockIdx.x * 128;
  const int kBase = blockIdx.z * kChunk;

  if (mode == 4 && tid < 128) { cs[tid] = 0.f; cq[tid] = 0.f; }

  const f32x4 fz = {0.f, 0.f, 0.f, 0.f};
  f32x4 acc[4][4];
#pragma unroll
  for (int m = 0; m < 4; m++)
#pragma unroll
    for (int n = 0; n < 4; n++) acc[m][n] = fz;

  const int sRow = lane >> 2;            // 0..15
  const int sCol = (lane & 3) * 8;       // 0,8,16,24
  const unsigned short* gA = A + (size_t)(mbase + w * 32 + sRow) * ld + sCol;
  const unsigned short* gB = B + (size_t)(nbase + w * 32 + sRow) * ld + sCol;
  unsigned short* lA0 = &Als[(w * 2 + 0) * 512];
  unsigned short* lA1 = &Als[(w * 2 + 1) * 512];
  unsigned short* lB0 = &Bls[(w * 2 + 0) * 512];
  unsigned short* lB1 = &Bls[(w * 2 + 1) * 512];

  const int rA = lane & 15, kg = (lane >> 4) * 8;

  for (int k0 = kBase; k0 < kBase + kChunk; k0 += 32) {
    __syncthreads();
    load_lds16(gA + k0, lA0);
    load_lds16(gA + (size_t)16 * ld + k0, lA1);
    load_lds16(gB + k0, lB0);
    load_lds16(gB + (size_t)16 * ld + k0, lB1);
    __syncthreads();
    bf16x8 a[4], b[4];
#pragma unroll
    for (int m = 0; m < 4; m++)
      a[m] = *(const bf16x8*)&Als[(wr * 64 + m * 16 + rA) * 32 + kg];
#pragma unroll
    for (int n = 0; n < 4; n++)
      b[n] = *(const bf16x8*)&Bls[(wc * 64 + n * 16 + rA) * 32 + kg];
#pragma unroll
    for (int m = 0; m < 4; m++)
#pragma unroll
      for (int n = 0; n < 4; n++)
        acc[m][n] = __builtin_amdgcn_mfma_f32_16x16x32_bf16(a[m], b[n], acc[m][n], 0, 0, 0);
  }

  // C/D layout: col = lane&15, row = (lane>>4)*4 + r   [m89-verified]
  const int crow0 = mbase + wr * 64 + (lane >> 4) * 4;
  const int ccol0 = nbase + wc * 64 + (lane & 15);

  if (mode == 4) {
    float mx = -2.0f;
#pragma unroll
    for (int n = 0; n < 4; n++) {
      float sv = 0.f, sq2 = 0.f;
#pragma unroll
      for (int m = 0; m < 4; m++)
#pragma unroll
        for (int r = 0; r < 4; r++) {
          const float val = acc[m][n][r];
          sv += val; sq2 += val * val;
          mx = fmaxf(mx, -val);
        }
      const int lcol = wc * 64 + n * 16 + (lane & 15);
      atomicAdd(&cs[lcol], sv);
      atomicAdd(&cq[lcol], sq2);
    }
#pragma unroll
    for (int off = 32; off; off >>= 1) mx = fmaxf(mx, __shfl_xor(mx, off));
    if (lane == 0) wmx[w] = mx;
    __syncthreads();
    if (tid == 0)
      atomicMax((int*)dmx, __float_as_int(fmaxf(fmaxf(wmx[0], wmx[1]), fmaxf(wmx[2], wmx[3]))));
    if (tid < 128) {
      atomicAdd(&psum[nbase + tid], cs[tid]);
      atomicAdd(&psq[nbase + tid], cq[tid]);
    }
    return;
  }

  float sArg = 0.f;
  if (mode == 2) sArg = 40.0f / ((1.0f + *dm1) * (1.0f + *dm2));
#pragma unroll
  for (int m = 0; m < 4; m++) {
#pragma unroll
    for (int n = 0; n < 4; n++) {
      const int col = ccol0 + n * 16;
      const float cv = (mode == 2) ? ctE[col] : 0.0f;
#pragma unroll
      for (int r = 0; r < 4; r++) {
        const int row = crow0 + m * 16 + r;
        float val = acc[m][n][r];
        if (mode == 3) {
          outf[((size_t)blockIdx.z * (gridDim.y * 128) + row) * ldo + col] = val;
        } else {
          if (mode == 2) val = __expf(fmaf(sArg, val, -cv));
          out[(size_t)row * ldo + col] = f2bf(val);
        }
      }
    }
  }
}

// ctE_j = [ (1-2*g2_j+s2_j)/m2^2 + (2/(m1*m2))*g2_j ] / eps
__global__ void k_ctfinal(const float* __restrict__ psum, const float* __restrict__ psq,
                          const float* __restrict__ dm1p, const float* __restrict__ dm2p,
                          float* __restrict__ ctE) {
  const int j = blockIdx.x * 256 + threadIdx.x;
  const float g2 = psum[j] * (1.0f / N4K);
  const float s2 = psq[j] * (1.0f / N4K);
  const float m1 = 1.0f + *dm1p, m2 = 1.0f + *dm2p;
  ctE[j] = ((1.0f - 2.0f * g2 + s2) / (m2 * m2) + (2.0f / (m1 * m2)) * g2) * 20.0f;
}

// ---------------- it=0: Yt0[d][i] = (1/N^2) * rowsum(X2t[d]) -----------------
__global__ void k_yt0(const unsigned short* __restrict__ X2t, unsigned short* __restrict__ Yt) {
  __shared__ float red[256];
  const int d = blockIdx.x, t = threadIdx.x;
  const unsigned short* row = X2t + (size_t)d * N4K;
  const uint4 q = *(const uint4*)&row[t * 16];
  const uint4 q2 = *(const uint4*)&row[t * 16 + 8];
  float s = bfl(q.x) + bfh(q.x) + bfl(q.y) + bfh(q.y) + bfl(q.z) + bfh(q.z)
          + bfl(q.w) + bfh(q.w) + bfl(q2.x) + bfh(q2.x) + bfl(q2.y) + bfh(q2.y)
          + bfl(q2.z) + bfh(q2.z) + bfl(q2.w) + bfh(q2.w);
  red[t] = s;
  __syncthreads();
  for (int st = 128; st > 0; st >>= 1) {
    if (t < st) red[t] += red[t + st];
    __syncthreads();
  }
  const unsigned short pv = f2bf(red[0] * (P_UNIF * P_UNIF));
  const unsigned pk = (unsigned)pv | ((unsigned)pv << 16);
  uint4* dst = (uint4*)(Yt + (size_t)d * N4K);
  dst[t] = make_uint4(pk, pk, pk, pk);
  dst[t + 256] = make_uint4(pk, pk, pk, pk);
}

// ---------------- X2vt[d][i] = X2t[d][i] * v[i] ------------------------------
__global__ void k_x2v(const unsigned short* __restrict__ X2t, const float* __restrict__ v,
                      unsigned short* __restrict__ X2vt) {
  const int d = blockIdx.x, t = threadIdx.x;
  const int i0 = t * 16;
  const unsigned short* src = X2t + (size_t)d * N4K + i0;
  unsigned short* dst = X2vt + (size_t)d * N4K + i0;
  const uint4 a = *(const uint4*)src;
  const uint4 b = *(const uint4*)(src + 8);
  const float4 v0 = *(const float4*)&v[i0];
  const float4 v1 = *(const float4*)&v[i0 + 4];
  const float4 v2 = *(const float4*)&v[i0 + 8];
  const float4 v3 = *(const float4*)&v[i0 + 12];
  unsigned r0 = (unsigned)f2bf(bfl(a.x) * v0.x) | ((unsigned)f2bf(bfh(a.x) * v0.y) << 16);
  unsigned r1 = (unsigned)f2bf(bfl(a.y) * v0.z) | ((unsigned)f2bf(bfh(a.y) * v0.w) << 16);
  unsigned r2 = (unsigned)f2bf(bfl(a.z) * v1.x) | ((unsigned)f2bf(bfh(a.z) * v1.y) << 16);
  unsigned r3 = (unsigned)f2bf(bfl(a.w) * v1.z) | ((unsigned)f2bf(bfh(a.w) * v1.w) << 16);
  unsigned r4 = (unsigned)f2bf(bfl(b.x) * v2.x) | ((unsigned)f2bf(bfh(b.x) * v2.y) << 16);
  unsigned r5 = (unsigned)f2bf(bfl(b.y) * v2.z) | ((unsigned)f2bf(bfh(b.y) * v2.w) << 16);
  unsigned r6 = (unsigned)f2bf(bfl(b.z) * v3.x) | ((unsigned)f2bf(bfh(b.z) * v3.y) << 16);
  unsigned r7 = (unsigned)f2bf(bfl(b.w) * v3.z) | ((unsigned)f2bf(bfh(b.w) * v3.w) << 16);
  *(uint4*)dst = make_uint4(r0, r1, r2, r3);
  *(uint4*)(dst + 8) = make_uint4(r4, r5, r6, r7);
}

// ---------------- reduce 4 K-chunk partials of Y, apply u, transpose ---------
// Yp: [4][4096][256] fp32 -> Yt: [256][4096] bf16, Yt[d][i] = u[i]*sum_z Yp[z][i][d]
__global__ void k_redY(const float* __restrict__ Yp, const float* __restrict__ u,
                       unsigned short* __restrict__ Yt) {
  __shared__ float t[64][65];
  const int tid = threadIdx.x;
  const int tx = tid & 63, ty = tid >> 6;
  const int r0 = blockIdx.x * 64, c0 = blockIdx.y * 64;
#pragma unroll
  for (int k = 0; k < 16; k++) {
    const int r = ty * 16 + k;
    const size_t off = (size_t)(r0 + r) * 256 + c0 + tx;
    float s = 0.f;
#pragma unroll
    for (int z = 0; z < 4; z++) s += Yp[(size_t)z * (N4K * 256) + off];
    t[r][tx] = s;
  }
  __syncthreads();
  const float uu = u[r0 + tx];
#pragma unroll
  for (int k = 0; k < 16; k++) {
    const int r = ty * 16 + k;
    Yt[(size_t)(c0 + r) * N4K + r0 + tx] = f2bf(t[tx][r] * uu);
  }
}

// ---------------- reduce 16 K-chunk partials of PT ---------------------------
__global__ void k_redPT(const float* __restrict__ Pp, unsigned short* __restrict__ PTb) {
  const int idx = blockIdx.x * 256 + threadIdx.x;
  float s = 0.f;
#pragma unroll
  for (int z = 0; z < 16; z++) s += Pp[z * 65536 + idx];
  PTb[idx] = f2bf(s);
}

// ---------------- fused Sinkhorn iteration (LDS-resident K slice) ------------
// 256 blocks x 512 thr, 16 rows/block staged once to LDS; both phases read LDS.
__global__ __launch_bounds__(512, 1) void k_sink(
    const unsigned short* __restrict__ Km, const float* __restrict__ vin,
    float* __restrict__ u, float* __restrict__ partials, int first, int last)
{
  __shared__ unsigned short Kl[16 * N4K];   // 128 KiB
  __shared__ float us[16];
  const int tid = threadIdx.x;
  const int wv = tid >> 6, lane = tid & 63;
  const int row0 = blockIdx.x * 16;
  // stage: wave wv loads its rows 2wv, 2wv+1 (16 KB) in 16 x 1KB chunks
  {
    const unsigned short* g = Km + (size_t)(row0 + wv * 2) * N4K + lane * 8;
    unsigned short* l = &Kl[wv * 2 * N4K];
#pragma unroll
    for (int i = 0; i < 16; i++)
      load_lds16(g + i * 512, l + i * 512);
  }
  __syncthreads();
  // phase A: u = p/(K v) for rows 2wv, 2wv+1
  {
    const unsigned short* rA = &Kl[(wv * 2) * N4K];
    const unsigned short* rB = rA + N4K;
    float accA = 0.f, accB = 0.f;
#pragma unroll
    for (int p = 0; p < 8; p++) {
      const int j0 = p * 512 + lane * 8;
      const uint4 qa = *(const uint4*)&rA[j0];
      const uint4 qb = *(const uint4*)&rB[j0];
      float4 xa, xb;
      if (first) { xa = make_float4(1.f, 1.f, 1.f, 1.f); xb = xa; }
      else { xa = *(const float4*)&vin[j0]; xb = *(const float4*)&vin[j0 + 4]; }
      accA += bfl(qa.x) * xa.x + bfh(qa.x) * xa.y + bfl(qa.y) * xa.z + bfh(qa.y) * xa.w
            + bfl(qa.z) * xb.x + bfh(qa.z) * xb.y + bfl(qa.w) * xb.z + bfh(qa.w) * xb.w;
      accB += bfl(qb.x) * xa.x + bfh(qb.x) * xa.y + bfl(qb.y) * xa.z + bfh(qb.y) * xa.w
            + bfl(qb.z) * xb.x + bfh(qb.z) * xb.y + bfl(qb.w) * xb.z + bfh(qb.w) * xb.w;
    }
#pragma unroll
    for (int off = 32; off; off >>= 1) {
      accA += __shfl_xor(accA, off);
      accB += __shfl_xor(accB, off);
    }
    if (lane == 0) {
      us[wv * 2] = P_UNIF / accA;
      us[wv * 2 + 1] = P_UNIF / accB;
    }
  }
  __syncthreads();
  // phase B: partial colsums of K^T u, 8 cols/thread, 16 rows from LDS
  {
    const int c0 = tid * 8;
    float a0 = 0, a1 = 0, a2 = 0, a3 = 0, a4 = 0, a5 = 0, a6 = 0, a7 = 0;
#pragma unroll
    for (int r = 0; r < 16; r++) {
      const float ur = us[r];
      const uint4 q = *(const uint4*)&Kl[r * N4K + c0];
      a0 += ur * bfl(q.x); a1 += ur * bfh(q.x);
      a2 += ur * bfl(q.y); a3 += ur * bfh(q.y);
      a4 += ur * bfl(q.z); a5 += ur * bfh(q.z);
      a6 += ur * bfl(q.w); a7 += ur * bfh(q.w);
    }
    float* pp = partials + (size_t)blockIdx.x * N4K + c0;
    *(float4*)pp = make_float4(a0, a1, a2, a3);
    *(float4*)(pp + 4) = make_float4(a4, a5, a6, a7);
  }
  if (last && tid < 16) u[row0 + tid] = us[tid];
}

// v_j = q / sum_{b<256} partials[b][j].  grid 128 x 256; block covers 32 cols.
__global__ void k_sinkfin(const float* __restrict__ partials, float* __restrict__ v) {
  __shared__ float red[8][32];
  const int tid = threadIdx.x;
  const int c = (blockIdx.x << 5) + (tid & 31);
  const int s = tid >> 5;                     // 0..7
  float acc = 0.f;
  const float* p = partials + (size_t)s * 32 * N4K + c;
#pragma unroll 8
  for (int b = 0; b < 32; b++) acc += p[(size_t)b * N4K];
  red[s][tid & 31] = acc;
  __syncthreads();
  if (s == 0) {
    float t = red[0][tid] + red[1][tid] + red[2][tid] + red[3][tid]
            + red[4][tid] + red[5][tid] + red[6][tid] + red[7][tid];
    v[c] = P_UNIF / t;
  }
}

// ---------------- loss = -sum log(u_i K_ii v_i + 1e-10) ----------------------
__global__ void k_loss(const unsigned short* __restrict__ K, const float* __restrict__ u,
                       const float* __restrict__ v, float* __restrict__ out) {
  const int tid = threadIdx.x;
  float acc = 0.f;
  for (int i = tid; i < N4K; i += 256) {
    const float d = u[i] * bfl((unsigned)K[(size_t)i * (N4K + 1)]) * v[i];
    acc += logf(d + 1e-10f);
  }
  __shared__ float red[256];
  red[tid] = acc;
  __syncthreads();
  for (int st = 128; st > 0; st >>= 1) {
    if (tid < st) red[tid] += red[tid + st];
    __syncthreads();
  }
  if (tid == 0) out[0] = -red[0];
}

// ============================================================================
extern "C" void kernel_launch(void* const* d_in, const int* in_sizes, int n_in,
                              void* d_out, int out_size, void* d_ws, size_t ws_size,
                              hipStream_t stream) {
  const float* f1 = (const float*)d_in[0];
  const float* f2 = (const float*)d_in[1];
  float* out = (float*)d_out;

  char* w = (char*)d_ws;
  const size_t NN = (size_t)N4K * N4K;
  unsigned short* X1 = (unsigned short*)w;   w += (size_t)N4K * DFEAT * 2;
  unsigned short* X2 = (unsigned short*)w;   w += (size_t)N4K * DFEAT * 2;
  unsigned short* X1t = (unsigned short*)w;  w += (size_t)N4K * DFEAT * 2;
  unsigned short* X2t = (unsigned short*)w;  w += (size_t)N4K * DFEAT * 2;
  unsigned short* X2vt = (unsigned short*)w; w += (size_t)N4K * DFEAT * 2;
  unsigned short* Zb = (unsigned short*)w;   w += (size_t)N4K * DFEAT * 2;
  unsigned short* Yt = (unsigned short*)w;   w += (size_t)N4K * DFEAT * 2;
  unsigned short* PTb = (unsigned short*)w;  w += (size_t)DFEAT * DFEAT * 2;
  unsigned short* KA = (unsigned short*)w;   w += NN * 2;
  unsigned short* KB = (unsigned short*)w;   w += NN * 2;
  float* Yp = (float*)w;    w += (size_t)4 * N4K * DFEAT * 4;    // 16 MB
  float* Pp = (float*)w;    w += (size_t)16 * DFEAT * DFEAT * 4; // 4 MB
  float* spart = (float*)w; w += (size_t)256 * N4K * 4;          // 4 MB
  float* stats = (float*)w; w += (size_t)16640 * 4;
  float* uvec = (float*)w;  w += N4K * 4;
  float* vvec = (float*)w;  w += N4K * 4;
  float* ctE = (float*)w;   w += N4K * 4;

  float* psum2 = stats;
  float* psq2 = stats + 4096;
  float* psumD = stats + 8192;
  float* psqD = stats + 12288;
  float* dmax1 = stats + 16384;
  float* dmax2 = stats + 16385;

  const dim3 b256(256);

  k_normalize<<<1024, b256, 0, stream>>>(f1, X1);
  k_normalize<<<1024, b256, 0, stream>>>(f2, X2);
  k_transpose<<<dim3(4, 64), b256, 0, stream>>>(X1, X1t, N4K, DFEAT);
  k_transpose<<<dim3(4, 64), b256, 0, stream>>>(X2, X2t, N4K, DFEAT);
  k_zerof<<<65, b256, 0, stream>>>(stats, 16640);

  // Gram stats (mode 4, no matrix output): G1 -> dmax1; G2 -> colsums + dmax2
  k_gemm_bt<<<dim3(32, 32, 1), b256, 0, stream>>>(X1, X1, DFEAT, DFEAT, nullptr, nullptr,
                                                  0, 4, nullptr, nullptr, nullptr,
                                                  psumD, psqD, dmax1);
  k_gemm_bt<<<dim3(32, 32, 1), b256, 0, stream>>>(X2, X2, DFEAT, DFEAT, nullptr, nullptr,
                                                  0, 4, nullptr, nullptr, nullptr,
                                                  psum2, psq2, dmax2);
  k_ctfinal<<<16, b256, 0, stream>>>(psum2, psq2, dmax1, dmax2, ctE);

  unsigned short* Kprev = nullptr;
  for (int it = 0; it < 5; it++) {
    if (it == 0) {
      // T0 = p q^T is rank-1: Yt0[d][i] = (1/N^2) rowsum(X2t[d])
      k_yt0<<<256, b256, 0, stream>>>(X2t, Yt);
    } else {
      // T = u (.) Kprev (.) v implicitly: Y = diag(u) Kprev (diag(v) X2)
      k_x2v<<<256, b256, 0, stream>>>(X2t, vvec, X2vt);
      k_gemm_bt<<<dim3(2, 32, 4), b256, 0, stream>>>(Kprev, X2vt, N4K, 1024, nullptr, Yp,
                                                     DFEAT, 3, nullptr, nullptr, nullptr,
                                                     nullptr, nullptr, nullptr);
      k_redY<<<dim3(64, 4), b256, 0, stream>>>(Yp, uvec, Yt);
    }
    // PT = Y^T X1 (K-split 16)
    k_gemm_bt<<<dim3(2, 2, 16), b256, 0, stream>>>(Yt, X1t, N4K, 256, nullptr, Pp,
                                                   DFEAT, 3, nullptr, nullptr, nullptr,
                                                   nullptr, nullptr, nullptr);
    k_redPT<<<256, b256, 0, stream>>>(Pp, PTb);
    // Z = X1 P
    k_gemm_bt<<<dim3(2, 32, 1), b256, 0, stream>>>(X1, PTb, DFEAT, DFEAT, Zb, nullptr,
                                                   DFEAT, 0, nullptr, nullptr, nullptr,
                                                   nullptr, nullptr, nullptr);
    // K = exp(sArg * Z X2^T - ctE_j)
    unsigned short* Knew = (Kprev == KA) ? KB : KA;
    k_gemm_bt<<<dim3(32, 32, 1), b256, 0, stream>>>(Zb, X2, DFEAT, DFEAT, Knew, nullptr,
                                                    N4K, 2, ctE, dmax1, dmax2,
                                                    nullptr, nullptr, nullptr);
    // Sinkhorn: 20 x { u = p/(K v) ; v = q/(K^T u) }, v0 = 1
    for (int s = 0; s < 20; s++) {
      k_sink<<<256, dim3(512), 0, stream>>>(Knew, vvec, uvec, spart,
                                            s == 0 ? 1 : 0, s == 19 ? 1 : 0);
      k_sinkfin<<<128, b256, 0, stream>>>(spart, vvec);
    }
    Kprev = Knew;
  }
  k_loss<<<1, b256, 0, stream>>>(Kprev, uvec, vvec, out);
}